// Round 1
// baseline (2382.169 us; speedup 1.0000x reference)
//
#include <hip/hip_runtime.h>
#include <hip/hip_bf16.h>
#include <math.h>

#define VOCAB 32000
#define DIM 1024
#define BB 2
#define SS 512
#define BS (BB*SS)
#define MASK_ID 31999
#define EXPAND_ID 31998
#define NSTEPS 4
#define TOPK 50
#define NR 8
#define NEGF (-3.4028234663852886e38f)

// -------- persistent device state (re-initialized every kernel_launch) ------
__device__ int   g_x[BS];
__device__ int   g_x0[BS];
__device__ int   g_tok_used[BS];
__device__ float g_conf[BS];
__device__ int   g_row_tok[NR];
__device__ float g_row_conf[NR];
__device__ int   g_row_x0[NR];
__device__ float g_h[NR][DIM];
__device__ float g_partial[4][NR][VOCAB];
__device__ float g_logits[NR][VOCAB];
__device__ float g_step_conf[NSTEPS];

__device__ inline unsigned keyf(float f) {
    unsigned b = __float_as_uint(f);
    return b ^ ((b & 0x80000000u) ? 0xFFFFFFFFu : 0x80000000u);
}

__global__ void k_init(const int* __restrict__ x) {
    int i = blockIdx.x * 256 + threadIdx.x;
    if (i < BS) {
        g_x[i] = x[i];
        g_tok_used[i] = -1;
        g_conf[i] = NEGF;
        g_x0[i] = 0;
    }
}

__global__ void k_reset_rows() {
    int i = threadIdx.x;
    if (i < NR) g_row_tok[i] = -1;
}

// Request a logit-row for every masked position whose predecessor token is
// not the one its cached conf was computed with. CAS-dedup into <=NR slots.
__global__ void k_requests() {
    int p = blockIdx.x * 256 + threadIdx.x;
    if (p >= BS) return;
    if (g_x[p] != MASK_ID) return;
    int s = p & (SS - 1);
    int t = g_x[(s == 0) ? p : p - 1];
    if (t == g_tok_used[p]) return;
    for (int r = 0; r < NR; r++) {
        int old = atomicCAS(&g_row_tok[r], -1, t);
        if (old == -1 || old == t) return;
    }
}

// h[r] = tanh(emb[tok_r] @ W1)   (zeros for inactive rows)
__global__ void k_h(const float* __restrict__ emb, const float* __restrict__ W1) {
    int r = blockIdx.x;
    int t = g_row_tok[r];
    if (t < 0) {
        for (int j = threadIdx.x; j < DIM; j += 256) g_h[r][j] = 0.f;
        return;
    }
    __shared__ float se[DIM];
    for (int j = threadIdx.x; j < DIM; j += 256) se[j] = emb[(size_t)t * DIM + j];
    __syncthreads();
    for (int j = threadIdx.x; j < DIM; j += 256) {
        float acc = 0.f;
        #pragma unroll 4
        for (int d = 0; d < DIM; d++) acc += se[d] * W1[(size_t)d * DIM + j];
        g_h[r][j] = tanhf(acc);
    }
}

// stage 1: partial logits; grid (VOCAB/128, 4 d-chunks), block 128
__global__ void k_logits1(const float* __restrict__ Wout) {
    int c  = blockIdx.x * 128 + threadIdx.x;
    int dc = blockIdx.y;
    __shared__ float sh[NR][256];
    for (int i = threadIdx.x; i < NR * 256; i += 128) {
        int r = i >> 8, dd = i & 255;
        sh[r][dd] = g_h[r][dc * 256 + dd];
    }
    __syncthreads();
    float acc[NR];
    #pragma unroll
    for (int r = 0; r < NR; r++) acc[r] = 0.f;
    const float* W = Wout + (size_t)dc * 256 * VOCAB + c;
    #pragma unroll 4
    for (int dd = 0; dd < 256; dd++) {
        float w = W[(size_t)dd * VOCAB];
        #pragma unroll
        for (int r = 0; r < NR; r++) acc[r] += sh[r][dd] * w;
    }
    #pragma unroll
    for (int r = 0; r < NR; r++) g_partial[dc][r][c] = acc[r];
}

// stage 2: deterministic combine + EXPAND penalty
__global__ void k_logits2() {
    int c = blockIdx.x * 256 + threadIdx.x;
    #pragma unroll
    for (int r = 0; r < NR; r++) {
        float v = g_partial[0][r][c] + g_partial[1][r][c]
                + g_partial[2][r][c] + g_partial[3][r][c];
        if (c == EXPAND_ID) v -= 1e9f;
        g_logits[r][c] = v;
    }
}

// per-row stats: max/argmax, Z, exact 50th-largest via radix select,
// top-p/top-k keep count, conf = 1/prefix.
__global__ void k_stats() {
    int r = blockIdx.x;
    if (g_row_tok[r] < 0) return;
    const float* L = g_logits[r];
    int tid = threadIdx.x;
    __shared__ float sv[256];
    __shared__ int   si[256];

    // pass 1: max + first-index argmax
    float bv = NEGF; int bi = 0x7fffffff;
    for (int i = tid; i < VOCAB; i += 256) {
        float v = L[i];
        if (v > bv) { bv = v; bi = i; }
    }
    sv[tid] = bv; si[tid] = bi;
    __syncthreads();
    for (int o = 128; o; o >>= 1) {
        if (tid < o) {
            if (sv[tid + o] > sv[tid] ||
                (sv[tid + o] == sv[tid] && si[tid + o] < si[tid])) {
                sv[tid] = sv[tid + o]; si[tid] = si[tid + o];
            }
        }
        __syncthreads();
    }
    __shared__ float s_max; __shared__ int s_amax;
    if (tid == 0) { s_max = sv[0]; s_amax = si[0]; }
    __syncthreads();
    float mx = s_max;

    // pass 2: Z = sum exp(l - mx) over all V
    float z = 0.f;
    for (int i = tid; i < VOCAB; i += 256) z += expf(L[i] - mx);
    sv[tid] = z;
    __syncthreads();
    for (int o = 128; o; o >>= 1) {
        if (tid < o) sv[tid] += sv[tid + o];
        __syncthreads();
    }
    __shared__ float s_Z;
    if (tid == 0) s_Z = sv[0];
    __syncthreads();
    float Z = s_Z;

    // radix select: exact key of the 50th-largest value
    __shared__ unsigned hist[256];
    __shared__ unsigned s_prefix; __shared__ int s_want;
    if (tid == 0) { s_prefix = 0u; s_want = TOPK; }
    __syncthreads();
    for (int shift = 24; shift >= 0; shift -= 8) {
        hist[tid] = 0u;
        __syncthreads();
        unsigned pref = s_prefix;
        unsigned maskAbove = (shift == 24) ? 0u : (0xFFFFFFFFu << (shift + 8));
        for (int i = tid; i < VOCAB; i += 256) {
            unsigned u = keyf(L[i]);
            if ((u & maskAbove) == (pref & maskAbove))
                atomicAdd(&hist[(u >> shift) & 255u], 1u);
        }
        __syncthreads();
        if (tid == 0) {
            unsigned cum = 0; int want = s_want; int b = 255;
            for (; b >= 0; b--) {
                unsigned cc = hist[b];
                if (cum + cc >= (unsigned)want) break;
                cum += cc;
            }
            s_prefix = pref | ((unsigned)b << shift);
            s_want = want - (int)cum;
        }
        __syncthreads();
    }
    unsigned kth = s_prefix;

    // gather all elements >= kth (exactly 50 for distinct floats)
    __shared__ float vals[64];
    __shared__ int s_cnt;
    if (tid == 0) s_cnt = 0;
    __syncthreads();
    for (int i = tid; i < VOCAB; i += 256) {
        if (keyf(L[i]) >= kth) {
            int j = atomicAdd(&s_cnt, 1);
            if (j < 64) vals[j] = L[i];
        }
    }
    __syncthreads();
    if (tid == 0) {
        int n = s_cnt; if (n > 64) n = 64;
        for (int a = 1; a < n; a++) {            // insertion sort, descending
            float v = vals[a]; int b = a - 1;
            while (b >= 0 && vals[b] < v) { vals[b + 1] = vals[b]; b--; }
            vals[b + 1] = v;
        }
        float run = expf(vals[0] - mx);          // == 1
        float lim = 0.9f * Z;
        for (int j = 1; j < n; j++) {
            if (run > lim) break;                // top-p removal boundary
            run += expf(vals[j] - mx);
        }
        g_row_conf[r] = 1.0f / run;
        g_row_x0[r]   = s_amax;
    }
}

// distribute row results to positions (by predecessor-token match)
__global__ void k_scatter() {
    int p = blockIdx.x * 256 + threadIdx.x;
    if (p >= BS) return;
    if (g_x[p] != MASK_ID) { g_conf[p] = NEGF; return; }
    int s = p & (SS - 1);
    int t = g_x[(s == 0) ? p : p - 1];
    #pragma unroll
    for (int r = 0; r < NR; r++) {
        if (g_row_tok[r] == t) {
            g_conf[p] = g_row_conf[r];
            g_x0[p]   = g_row_x0[r];
            g_tok_used[p] = t;
            return;
        }
    }
}

// global first-index argmax over conf; reveal one token
__global__ void k_select(int step) {
    __shared__ float sv[1024];
    __shared__ int   si[1024];
    int tid = threadIdx.x;
    sv[tid] = g_conf[tid]; si[tid] = tid;
    __syncthreads();
    for (int o = 512; o; o >>= 1) {
        if (tid < o) {
            if (sv[tid + o] > sv[tid] ||
                (sv[tid + o] == sv[tid] && si[tid + o] < si[tid])) {
                sv[tid] = sv[tid + o]; si[tid] = si[tid + o];
            }
        }
        __syncthreads();
    }
    if (tid == 0) {
        float c = sv[0]; int idx = si[0];
        g_step_conf[step] = c;
        if (c > 0.f) g_x[idx] = g_x0[idx];   // any-mask guard: conf >= 1/50 > 0
    }
}

__global__ void k_out(float* __restrict__ out) {
    int i = blockIdx.x * 256 + threadIdx.x;
    if (i < BS) out[i] = (float)g_x[i];
    else if (i < BS + NSTEPS) out[i] = g_step_conf[i - BS];
}

extern "C" void kernel_launch(void* const* d_in, const int* in_sizes, int n_in,
                              void* d_out, int out_size, void* d_ws, size_t ws_size,
                              hipStream_t stream) {
    const int*   x    = (const int*)  d_in[0];
    const float* emb  = (const float*)d_in[1];
    const float* W1   = (const float*)d_in[2];
    const float* Wout = (const float*)d_in[3];

    k_init<<<(BS + 255) / 256, 256, 0, stream>>>(x);
    for (int s = 0; s < NSTEPS; s++) {
        k_reset_rows<<<1, NR, 0, stream>>>();
        k_requests<<<(BS + 255) / 256, 256, 0, stream>>>();
        k_h<<<NR, 256, 0, stream>>>(emb, W1);
        k_logits1<<<dim3(VOCAB / 128, 4), 128, 0, stream>>>(Wout);
        k_logits2<<<VOCAB / 256, 256, 0, stream>>>();
        k_stats<<<NR, 256, 0, stream>>>();
        k_scatter<<<(BS + 255) / 256, 256, 0, stream>>>();
        k_select<<<1, 1024, 0, stream>>>(s);
    }
    k_out<<<(BS + NSTEPS + 255) / 256, 256, 0, stream>>>((float*)d_out);
}

// Round 2
// 1077.513 us; speedup vs baseline: 2.2108x; 2.2108x over previous
//
#include <hip/hip_runtime.h>
#include <hip/hip_bf16.h>
#include <math.h>

#define VOCAB 32000
#define DIM 1024
#define BB 2
#define SS 512
#define BS (BB*SS)
#define MASK_ID 31999
#define EXPAND_ID 31998
#define NSTEPS 4
#define TOPK 50
#define NR 8
#define NEGF (-3.4028234663852886e38f)

// h split-K geometry
#define NDC_H 16
#define DH 64
// logits split-K geometry
#define NDCL 8
#define DL 128
#define LCOLS_BLK 512                 // 128 threads * 4 cols
#define LNBX ((VOCAB + LCOLS_BLK - 1) / LCOLS_BLK)   // 63

// -------- persistent device state (re-initialized every kernel_launch) ------
__device__ int   g_x[BS];
__device__ int   g_x0[BS];
__device__ int   g_tok_used[BS];
__device__ float g_conf[BS];
__device__ int   g_row_tok[NR];
__device__ float g_row_conf[NR];
__device__ int   g_row_x0[NR];
__device__ float g_h_part[NDC_H][NR][DIM];
__device__ float g_h[NR][DIM];
__device__ float g_lpart[NDCL][NR][VOCAB];
__device__ float g_logits[NR][VOCAB];
__device__ float g_step_conf[NSTEPS];

__device__ inline unsigned keyf(float f) {
    unsigned b = __float_as_uint(f);
    return b ^ ((b & 0x80000000u) ? 0xFFFFFFFFu : 0x80000000u);
}

__global__ void k_init(const int* __restrict__ x) {
    int i = blockIdx.x * 256 + threadIdx.x;
    if (i < BS) {
        g_x[i] = x[i];
        g_tok_used[i] = -1;
        g_conf[i] = NEGF;
        g_x0[i] = 0;
    }
}

// single block, 1024 threads: reset row slots + CAS-dedup requests
__global__ void k_requests() {
    int p = threadIdx.x;
    if (p < NR) g_row_tok[p] = -1;
    __syncthreads();
    if (g_x[p] != MASK_ID) return;
    int s = p & (SS - 1);
    int t = g_x[(s == 0) ? p : p - 1];
    if (t == g_tok_used[p]) return;
    for (int r = 0; r < NR; r++) {
        int old = atomicCAS(&g_row_tok[r], -1, t);
        if (old == -1 || old == t) return;
    }
}

// h partials: grid (DIM/128, NDC_H), block 128
__global__ void k_h_part(const float* __restrict__ emb, const float* __restrict__ W1) {
    int col = blockIdx.x * 128 + threadIdx.x;
    int dc  = blockIdx.y;
    int dbase = dc * DH;
    __shared__ float se[NR][DH];          // 8*64*4 = 2 KB
    for (int i = threadIdx.x; i < NR * DH; i += 128) {
        int r = i >> 6, dd = i & (DH - 1);
        int t = g_row_tok[r];
        se[r][dd] = (t < 0) ? 0.f : emb[(size_t)t * DIM + dbase + dd];
    }
    __syncthreads();
    float acc[NR];
    #pragma unroll
    for (int r = 0; r < NR; r++) acc[r] = 0.f;
    #pragma unroll 4
    for (int dd = 0; dd < DH; dd++) {
        float w = W1[(size_t)(dbase + dd) * DIM + col];
        #pragma unroll
        for (int r = 0; r < NR; r++) acc[r] += se[r][dd] * w;
    }
    #pragma unroll
    for (int r = 0; r < NR; r++) g_h_part[dc][r][col] = acc[r];
}

// combine + tanh: grid 32, block 256
__global__ void k_h_comb() {
    int idx = blockIdx.x * 256 + threadIdx.x;     // 0..8191
    int r = idx >> 10, c = idx & (DIM - 1);
    float v = 0.f;
    #pragma unroll
    for (int dc = 0; dc < NDC_H; dc++) v += g_h_part[dc][r][c];
    g_h[r][c] = tanhf(v);
}

// logits partials: grid (LNBX, NDCL), block 128, float4 columns
__global__ void k_logits_part(const float* __restrict__ Wout) {
    int c  = blockIdx.x * LCOLS_BLK + threadIdx.x * 4;
    int dc = blockIdx.y;
    __shared__ float sh[NR][DL];          // 4 KB
    for (int i = threadIdx.x; i < NR * DL; i += 128) {
        int r = i >> 7, dd = i & (DL - 1);
        sh[r][dd] = g_h[r][dc * DL + dd];
    }
    __syncthreads();
    if (c >= VOCAB) return;
    float4 acc[NR];
    #pragma unroll
    for (int r = 0; r < NR; r++) acc[r] = make_float4(0.f, 0.f, 0.f, 0.f);
    const float* W = Wout + (size_t)dc * DL * VOCAB + c;
    #pragma unroll 2
    for (int dd = 0; dd < DL; dd++) {
        float4 w = *(const float4*)(W + (size_t)dd * VOCAB);
        #pragma unroll
        for (int r = 0; r < NR; r++) {
            float s = sh[r][dd];
            acc[r].x += s * w.x; acc[r].y += s * w.y;
            acc[r].z += s * w.z; acc[r].w += s * w.w;
        }
    }
    #pragma unroll
    for (int r = 0; r < NR; r++)
        *(float4*)&g_lpart[dc][r][c] = acc[r];
}

// combine + EXPAND penalty: grid 125, block 256
__global__ void k_logits_comb() {
    int c = blockIdx.x * 256 + threadIdx.x;
    #pragma unroll
    for (int r = 0; r < NR; r++) {
        float v = 0.f;
        #pragma unroll
        for (int dc = 0; dc < NDCL; dc++) v += g_lpart[dc][r][c];
        if (c == EXPAND_ID) v -= 1e9f;
        g_logits[r][c] = v;
    }
}

// per-row stats: max/argmax, Z, exact 50th-largest via radix select,
// top-p/top-k keep count, conf = 1/prefix.
__global__ void k_stats() {
    int r = blockIdx.x;
    if (g_row_tok[r] < 0) return;
    const float* L = g_logits[r];
    int tid = threadIdx.x;
    __shared__ float sv[256];
    __shared__ int   si[256];

    // pass 1: max + first-index argmax
    float bv = NEGF; int bi = 0x7fffffff;
    for (int i = tid; i < VOCAB; i += 256) {
        float v = L[i];
        if (v > bv) { bv = v; bi = i; }
    }
    sv[tid] = bv; si[tid] = bi;
    __syncthreads();
    for (int o = 128; o; o >>= 1) {
        if (tid < o) {
            if (sv[tid + o] > sv[tid] ||
                (sv[tid + o] == sv[tid] && si[tid + o] < si[tid])) {
                sv[tid] = sv[tid + o]; si[tid] = si[tid + o];
            }
        }
        __syncthreads();
    }
    __shared__ float s_max; __shared__ int s_amax;
    if (tid == 0) { s_max = sv[0]; s_amax = si[0]; }
    __syncthreads();
    float mx = s_max;

    // pass 2: Z = sum exp(l - mx)
    float z = 0.f;
    for (int i = tid; i < VOCAB; i += 256) z += expf(L[i] - mx);
    sv[tid] = z;
    __syncthreads();
    for (int o = 128; o; o >>= 1) {
        if (tid < o) sv[tid] += sv[tid + o];
        __syncthreads();
    }
    __shared__ float s_Z;
    if (tid == 0) s_Z = sv[0];
    __syncthreads();
    float Z = s_Z;

    // radix select: exact key of the 50th-largest value
    __shared__ unsigned hist[256];
    __shared__ unsigned s_prefix; __shared__ int s_want;
    if (tid == 0) { s_prefix = 0u; s_want = TOPK; }
    __syncthreads();
    for (int shift = 24; shift >= 0; shift -= 8) {
        hist[tid] = 0u;
        __syncthreads();
        unsigned pref = s_prefix;
        unsigned maskAbove = (shift == 24) ? 0u : (0xFFFFFFFFu << (shift + 8));
        for (int i = tid; i < VOCAB; i += 256) {
            unsigned u = keyf(L[i]);
            if ((u & maskAbove) == (pref & maskAbove))
                atomicAdd(&hist[(u >> shift) & 255u], 1u);
        }
        __syncthreads();
        if (tid == 0) {
            unsigned cum = 0; int want = s_want; int b = 255;
            for (; b >= 0; b--) {
                unsigned cc = hist[b];
                if (cum + cc >= (unsigned)want) break;
                cum += cc;
            }
            s_prefix = pref | ((unsigned)b << shift);
            s_want = want - (int)cum;
        }
        __syncthreads();
    }
    unsigned kth = s_prefix;

    // gather all elements >= kth (exactly 50 for distinct floats)
    __shared__ float vals[64];
    __shared__ int s_cnt;
    if (tid == 0) s_cnt = 0;
    __syncthreads();
    for (int i = tid; i < VOCAB; i += 256) {
        if (keyf(L[i]) >= kth) {
            int j = atomicAdd(&s_cnt, 1);
            if (j < 64) vals[j] = L[i];
        }
    }
    __syncthreads();
    if (tid == 0) {
        int n = s_cnt; if (n > 64) n = 64;
        for (int a = 1; a < n; a++) {            // insertion sort, descending
            float v = vals[a]; int b = a - 1;
            while (b >= 0 && vals[b] < v) { vals[b + 1] = vals[b]; b--; }
            vals[b + 1] = v;
        }
        float run = expf(vals[0] - mx);          // == 1
        float lim = 0.9f * Z;
        for (int j = 1; j < n; j++) {
            if (run > lim) break;                // top-p removal boundary
            run += expf(vals[j] - mx);
        }
        g_row_conf[r] = 1.0f / run;
        g_row_x0[r]   = s_amax;
    }
}

// single block, 1024 threads: scatter row results + global argmax + reveal
__global__ void k_scatter_select(int step) {
    __shared__ float sv[1024];
    __shared__ int   si[1024];
    int p = threadIdx.x;
    if (g_x[p] != MASK_ID) {
        g_conf[p] = NEGF;
    } else {
        int s = p & (SS - 1);
        int t = g_x[(s == 0) ? p : p - 1];
        #pragma unroll
        for (int r = 0; r < NR; r++) {
            if (g_row_tok[r] == t) {
                g_conf[p] = g_row_conf[r];
                g_x0[p]   = g_row_x0[r];
                g_tok_used[p] = t;
                break;
            }
        }
    }
    __syncthreads();
    sv[p] = g_conf[p]; si[p] = p;
    __syncthreads();
    for (int o = 512; o; o >>= 1) {
        if (p < o) {
            if (sv[p + o] > sv[p] ||
                (sv[p + o] == sv[p] && si[p + o] < si[p])) {
                sv[p] = sv[p + o]; si[p] = si[p + o];
            }
        }
        __syncthreads();
    }
    if (p == 0) {
        float c = sv[0]; int idx = si[0];
        g_step_conf[step] = c;
        if (c > 0.f) g_x[idx] = g_x0[idx];   // any-mask guard: conf > 0
    }
}

__global__ void k_out(float* __restrict__ out) {
    int i = blockIdx.x * 256 + threadIdx.x;
    if (i < BS) out[i] = (float)g_x[i];
    else if (i < BS + NSTEPS) out[i] = g_step_conf[i - BS];
}

extern "C" void kernel_launch(void* const* d_in, const int* in_sizes, int n_in,
                              void* d_out, int out_size, void* d_ws, size_t ws_size,
                              hipStream_t stream) {
    const int*   x    = (const int*)  d_in[0];
    const float* emb  = (const float*)d_in[1];
    const float* W1   = (const float*)d_in[2];
    const float* Wout = (const float*)d_in[3];

    k_init<<<(BS + 255) / 256, 256, 0, stream>>>(x);
    for (int s = 0; s < NSTEPS; s++) {
        k_requests<<<1, 1024, 0, stream>>>();
        k_h_part<<<dim3(DIM / 128, NDC_H), 128, 0, stream>>>(emb, W1);
        k_h_comb<<<32, 256, 0, stream>>>();
        k_logits_part<<<dim3(LNBX, NDCL), 128, 0, stream>>>(Wout);
        k_logits_comb<<<VOCAB / 256, 256, 0, stream>>>();
        k_stats<<<NR, 256, 0, stream>>>();
        k_scatter_select<<<1, 1024, 0, stream>>>(s);
    }
    k_out<<<(BS + NSTEPS + 255) / 256, 256, 0, stream>>>((float*)d_out);
}

// Round 3
// 573.605 us; speedup vs baseline: 4.1530x; 1.8785x over previous
//
#include <hip/hip_runtime.h>
#include <hip/hip_bf16.h>
#include <math.h>

#define VOCAB 32000
#define DIM 1024
#define BB 2
#define SS 512
#define BS (BB*SS)
#define MASK_ID 31999
#define EXPAND_ID 31998
#define NSTEPS 4
#define TOPK 50
#define NR 8
#define NEGF (-3.4028234663852886e38f)

// h split-K geometry
#define NDC_H 16
#define DH 64
// logits split-K geometry
#define NDCL 16
#define DL 64
#define LCOLS_BLK 512                 // 128 threads * 4 cols
#define LNBX 63                      // ceil(32000/512)
// stats geometry
#define EPT 32                        // 32 regs/thread * 1024 threads = 32768 >= VOCAB

// -------- persistent device state (re-initialized every kernel_launch) ------
__device__ int   g_x[BS];
__device__ int   g_x0[BS];
__device__ int   g_tok_used[BS];
__device__ float g_conf[BS];
__device__ int   g_row_tok[NR];
__device__ float g_row_conf[NR];
__device__ int   g_row_x0[NR];
__device__ float g_h_part[NDC_H][NR][DIM];
__device__ float g_h[NR][DIM];
__device__ float g_lpart[NDCL][NR][VOCAB];
__device__ float g_logits[NR][VOCAB];
__device__ float g_step_conf[NSTEPS];

__device__ inline unsigned keyf(float f) {
    unsigned b = __float_as_uint(f);
    return b ^ ((b & 0x80000000u) ? 0xFFFFFFFFu : 0x80000000u);
}

__global__ void k_init(const int* __restrict__ x) {
    int i = blockIdx.x * 256 + threadIdx.x;
    if (i < BS) {
        g_x[i] = x[i];
        g_tok_used[i] = -1;
        g_conf[i] = NEGF;
        g_x0[i] = 0;
    }
}

// single block, 1024 threads: reset row slots + CAS-dedup requests (step 0)
__global__ __launch_bounds__(1024) void k_requests() {
    int p = threadIdx.x;
    if (p < NR) g_row_tok[p] = -1;
    __syncthreads();
    if (g_x[p] != MASK_ID) return;
    int s = p & (SS - 1);
    int t = g_x[(s == 0) ? p : p - 1];
    if (t == g_tok_used[p]) return;
    for (int r = 0; r < NR; r++) {
        int old = atomicCAS(&g_row_tok[r], -1, t);
        if (old == -1 || old == t) return;
    }
}

// h partials: grid (DIM/128, NDC_H), block 128
__global__ void k_h_part(const float* __restrict__ emb, const float* __restrict__ W1) {
    int col = blockIdx.x * 128 + threadIdx.x;
    int dc  = blockIdx.y;
    int dbase = dc * DH;
    __shared__ float se[NR][DH];          // 2 KB
    for (int i = threadIdx.x; i < NR * DH; i += 128) {
        int r = i >> 6, dd = i & (DH - 1);
        int t = g_row_tok[r];
        se[r][dd] = (t < 0) ? 0.f : emb[(size_t)t * DIM + dbase + dd];
    }
    __syncthreads();
    float acc[NR];
    #pragma unroll
    for (int r = 0; r < NR; r++) acc[r] = 0.f;
    #pragma unroll 4
    for (int dd = 0; dd < DH; dd++) {
        float w = W1[(size_t)(dbase + dd) * DIM + col];
        #pragma unroll
        for (int r = 0; r < NR; r++) acc[r] += se[r][dd] * w;
    }
    #pragma unroll
    for (int r = 0; r < NR; r++) g_h_part[dc][r][col] = acc[r];
}

// combine + tanh: grid 32, block 256
__global__ void k_h_comb() {
    int idx = blockIdx.x * 256 + threadIdx.x;     // 0..8191
    int r = idx >> 10, c = idx & (DIM - 1);
    float v = 0.f;
    #pragma unroll
    for (int dc = 0; dc < NDC_H; dc++) v += g_h_part[dc][r][c];
    g_h[r][c] = tanhf(v);
}

// logits partials: grid (LNBX, NDCL), block 128, float4 columns
__global__ void k_logits_part(const float* __restrict__ Wout) {
    int c  = blockIdx.x * LCOLS_BLK + threadIdx.x * 4;
    int dc = blockIdx.y;
    __shared__ float sh[NR][DL];          // 2 KB
    __shared__ int s_act[NR];
    if (threadIdx.x < NR) s_act[threadIdx.x] = (g_row_tok[threadIdx.x] >= 0);
    for (int i = threadIdx.x; i < NR * DL; i += 128) {
        int r = i >> 6, dd = i & (DL - 1);
        sh[r][dd] = g_h[r][dc * DL + dd];
    }
    __syncthreads();
    if (c >= VOCAB) return;
    float4 acc[NR];
    #pragma unroll
    for (int r = 0; r < NR; r++) acc[r] = make_float4(0.f, 0.f, 0.f, 0.f);
    const float* W = Wout + (size_t)dc * DL * VOCAB + c;
    #pragma unroll 2
    for (int dd = 0; dd < DL; dd++) {
        float4 w = *(const float4*)(W + (size_t)dd * VOCAB);
        #pragma unroll
        for (int r = 0; r < NR; r++) {
            float s = sh[r][dd];
            acc[r].x += s * w.x; acc[r].y += s * w.y;
            acc[r].z += s * w.z; acc[r].w += s * w.w;
        }
    }
    #pragma unroll
    for (int r = 0; r < NR; r++)
        if (s_act[r]) *(float4*)&g_lpart[dc][r][c] = acc[r];
}

// combine + EXPAND penalty: grid 125, block 256 (active rows only)
__global__ void k_logits_comb() {
    int c = blockIdx.x * 256 + threadIdx.x;
    #pragma unroll
    for (int r = 0; r < NR; r++) {
        if (g_row_tok[r] < 0) continue;
        float v = 0.f;
        #pragma unroll
        for (int dc = 0; dc < NDCL; dc++) v += g_lpart[dc][r][c];
        if (c == EXPAND_ID) v -= 1e9f;
        g_logits[r][c] = v;
    }
}

// per-row stats in registers: one global read, then max/argmax, Z,
// exact 50th-largest via 4x8-bit radix select, top-p keep count, conf.
__global__ __launch_bounds__(1024) void k_stats() {
    int r = blockIdx.x;
    if (g_row_tok[r] < 0) return;
    const float* L = g_logits[r];
    int tid = threadIdx.x;

    float v[EPT];
    #pragma unroll
    for (int i = 0; i < EPT; i++) {
        int c = i * 1024 + tid;
        v[i] = (c < VOCAB) ? L[c] : NEGF;
    }

    __shared__ float sv[1024];
    __shared__ int   si[1024];

    // pass 1: max + first-index argmax (register sweep)
    float bv = NEGF; int bi = 0x7fffffff;
    #pragma unroll
    for (int i = 0; i < EPT; i++) {
        if (v[i] > bv) { bv = v[i]; bi = i * 1024 + tid; }
    }
    sv[tid] = bv; si[tid] = bi;
    __syncthreads();
    for (int o = 512; o; o >>= 1) {
        if (tid < o) {
            if (sv[tid + o] > sv[tid] ||
                (sv[tid + o] == sv[tid] && si[tid + o] < si[tid])) {
                sv[tid] = sv[tid + o]; si[tid] = si[tid + o];
            }
        }
        __syncthreads();
    }
    __shared__ float s_max; __shared__ int s_amax;
    if (tid == 0) { s_max = sv[0]; s_amax = si[0]; }
    __syncthreads();
    float mx = s_max;

    // pass 2: Z = sum exp(l - mx) (register sweep; invalid lanes give exp(-inf)=0)
    float z = 0.f;
    #pragma unroll
    for (int i = 0; i < EPT; i++) z += expf(v[i] - mx);
    sv[tid] = z;
    __syncthreads();
    for (int o = 512; o; o >>= 1) {
        if (tid < o) sv[tid] += sv[tid + o];
        __syncthreads();
    }
    __shared__ float s_Z;
    if (tid == 0) s_Z = sv[0];
    __syncthreads();
    float Z = s_Z;

    // radix select on register data: exact key of the 50th-largest
    __shared__ unsigned hist[256];
    __shared__ unsigned s_prefix; __shared__ int s_want;
    if (tid == 0) { s_prefix = 0u; s_want = TOPK; }
    __syncthreads();
    for (int shift = 24; shift >= 0; shift -= 8) {
        if (tid < 256) hist[tid] = 0u;
        __syncthreads();
        unsigned pref = s_prefix;
        unsigned maskAbove = (shift == 24) ? 0u : (0xFFFFFFFFu << (shift + 8));
        #pragma unroll
        for (int i = 0; i < EPT; i++) {
            unsigned u = keyf(v[i]);
            if ((u & maskAbove) == (pref & maskAbove))
                atomicAdd(&hist[(u >> shift) & 255u], 1u);
        }
        __syncthreads();
        if (tid == 0) {
            unsigned cum = 0; int want = s_want; int b = 255;
            for (; b >= 0; b--) {
                unsigned cc = hist[b];
                if (cum + cc >= (unsigned)want) break;
                cum += cc;
            }
            s_prefix = pref | ((unsigned)b << shift);
            s_want = want - (int)cum;
        }
        __syncthreads();
    }
    unsigned kth = s_prefix;

    // gather all elements >= kth (exactly TOPK for distinct floats)
    __shared__ float vals[64];
    __shared__ int s_cnt;
    if (tid == 0) s_cnt = 0;
    __syncthreads();
    #pragma unroll
    for (int i = 0; i < EPT; i++) {
        if (keyf(v[i]) >= kth) {
            int j = atomicAdd(&s_cnt, 1);
            if (j < 64) vals[j] = v[i];
        }
    }
    __syncthreads();
    if (tid == 0) {
        int n = s_cnt; if (n > 64) n = 64;
        for (int a = 1; a < n; a++) {            // insertion sort, descending
            float vv = vals[a]; int b = a - 1;
            while (b >= 0 && vals[b] < vv) { vals[b + 1] = vals[b]; b--; }
            vals[b + 1] = vv;
        }
        float run = expf(vals[0] - mx);          // == 1
        float lim = 0.9f * Z;
        for (int j = 1; j < n; j++) {
            if (run > lim) break;                // top-p removal boundary
            run += expf(vals[j] - mx);
        }
        g_row_conf[r] = 1.0f / run;
        g_row_x0[r]   = s_amax;
    }
}

// single block, 1024 threads: scatter + global argmax + reveal + NEXT requests
__global__ __launch_bounds__(1024) void k_scatter_select(int step) {
    __shared__ float sv[1024];
    __shared__ int   si[1024];
    int p = threadIdx.x;
    float myconf;
    if (g_x[p] != MASK_ID) {
        myconf = NEGF; g_conf[p] = NEGF;
    } else {
        myconf = g_conf[p];                       // cached from earlier steps
        int s = p & (SS - 1);
        int t = g_x[(s == 0) ? p : p - 1];
        #pragma unroll
        for (int r = 0; r < NR; r++) {
            if (g_row_tok[r] == t) {
                myconf = g_row_conf[r];
                g_conf[p] = myconf;
                g_x0[p]   = g_row_x0[r];
                g_tok_used[p] = t;
                break;
            }
        }
    }
    sv[p] = myconf; si[p] = p;
    __syncthreads();
    for (int o = 512; o; o >>= 1) {
        if (p < o) {
            if (sv[p + o] > sv[p] ||
                (sv[p + o] == sv[p] && si[p + o] < si[p])) {
                sv[p] = sv[p + o]; si[p] = si[p + o];
            }
        }
        __syncthreads();
    }
    if (p == 0) {
        float c = sv[0]; int idx = si[0];
        g_step_conf[step] = c;
        if (c > 0.f) g_x[idx] = g_x0[idx];        // any-mask guard: conf > 0
    }
    __syncthreads();
    // ---- next-step requests (post-reveal) ----
    if (p < NR) g_row_tok[p] = -1;
    __syncthreads();
    if (g_x[p] != MASK_ID) return;
    int s2 = p & (SS - 1);
    int t2 = g_x[(s2 == 0) ? p : p - 1];
    if (t2 == g_tok_used[p]) return;
    for (int r = 0; r < NR; r++) {
        int old = atomicCAS(&g_row_tok[r], -1, t2);
        if (old == -1 || old == t2) return;
    }
}

__global__ void k_out(float* __restrict__ out) {
    int i = blockIdx.x * 256 + threadIdx.x;
    if (i < BS) out[i] = (float)g_x[i];
    else if (i < BS + NSTEPS) out[i] = g_step_conf[i - BS];
}

extern "C" void kernel_launch(void* const* d_in, const int* in_sizes, int n_in,
                              void* d_out, int out_size, void* d_ws, size_t ws_size,
                              hipStream_t stream) {
    const int*   x    = (const int*)  d_in[0];
    const float* emb  = (const float*)d_in[1];
    const float* W1   = (const float*)d_in[2];
    const float* Wout = (const float*)d_in[3];

    k_init<<<(BS + 255) / 256, 256, 0, stream>>>(x);
    k_requests<<<1, 1024, 0, stream>>>();
    for (int s = 0; s < NSTEPS; s++) {
        k_h_part<<<dim3(DIM / 128, NDC_H), 128, 0, stream>>>(emb, W1);
        k_h_comb<<<32, 256, 0, stream>>>();
        k_logits_part<<<dim3(LNBX, NDCL), 128, 0, stream>>>(Wout);
        k_logits_comb<<<VOCAB / 256, 256, 0, stream>>>();
        k_stats<<<NR, 1024, 0, stream>>>();
        k_scatter_select<<<1, 1024, 0, stream>>>(s);
    }
    k_out<<<(BS + NSTEPS + 255) / 256, 256, 0, stream>>>((float*)d_out);
}

// Round 4
// 340.206 us; speedup vs baseline: 7.0021x; 1.6861x over previous
//
#include <hip/hip_runtime.h>
#include <hip/hip_bf16.h>
#include <math.h>

#define VOCAB 32000
#define DIM 1024
#define BB 2
#define SS 512
#define BS (BB*SS)
#define MASK_ID 31999
#define EXPAND_ID 31998
#define NSTEPS 4
#define TOPK 50
#define NR 8
#define NEGF (-3.4028234663852886e38f)

// h split-K geometry
#define NDC_H 16
#define DH 64
// logits split-K geometry
#define NDCL 16
#define DL 64
#define LCOLS_BLK 512                 // 128 threads * 4 cols
#define LNBX 63                       // ceil(32000/512)
#define NCHUNK 125                    // 32000 / 256
#define CAND_CAP 512

// -------- persistent device state (re-initialized every kernel_launch) ------
__device__ int      g_x[BS];
__device__ int      g_x0[BS];
__device__ int      g_tok_used[BS];
__device__ float    g_conf[BS];
__device__ int      g_row_tok[NR];
__device__ float    g_row_conf[NR];
__device__ int      g_row_x0[NR];
__device__ float    g_h_part[NDC_H][NR][DIM];
__device__ float    g_h[NR][DIM];
__device__ float    g_lpart[NDCL][NR][VOCAB];
__device__ float    g_logits[NR][VOCAB];
__device__ float    g_step_conf[NSTEPS];
// stats pipeline state
__device__ unsigned g_hist16[NR][65536];
__device__ float    g_cmax[NR][128];
__device__ int      g_camax[NR][128];
__device__ float    g_cz[NR][128];
__device__ unsigned g_thr[NR];
__device__ float    g_mx_r[NR];
__device__ float    g_Z_r[NR];
__device__ int      g_amax_r[NR];
__device__ int      g_cand_cnt[NR];
__device__ float    g_cand[NR][CAND_CAP];

__device__ inline unsigned keyf(float f) {
    unsigned b = __float_as_uint(f);
    return b ^ ((b & 0x80000000u) ? 0xFFFFFFFFu : 0x80000000u);
}

__global__ void k_init(const int* __restrict__ x) {
    int i = blockIdx.x * 256 + threadIdx.x;
    if (i < BS) {
        g_x[i] = x[i];
        g_tok_used[i] = -1;
        g_conf[i] = NEGF;
        g_x0[i] = 0;
    }
}

// single block, 1024 threads: reset row slots + CAS-dedup requests (step 0)
__global__ __launch_bounds__(1024) void k_requests() {
    int p = threadIdx.x;
    if (p < NR) g_row_tok[p] = -1;
    __syncthreads();
    if (g_x[p] != MASK_ID) return;
    int s = p & (SS - 1);
    int t = g_x[(s == 0) ? p : p - 1];
    if (t == g_tok_used[p]) return;
    for (int r = 0; r < NR; r++) {
        int old = atomicCAS(&g_row_tok[r], -1, t);
        if (old == -1 || old == t) return;
    }
}

// h partials + fused histogram zero: grid (DIM/128, NDC_H), block 128
__global__ void k_h_part(const float* __restrict__ emb, const float* __restrict__ W1) {
    int col = blockIdx.x * 128 + threadIdx.x;
    int dc  = blockIdx.y;
    int dbase = dc * DH;
    __shared__ float se[NR][DH];          // 2 KB
    for (int i = threadIdx.x; i < NR * DH; i += 128) {
        int r = i >> 6, dd = i & (DH - 1);
        int t = g_row_tok[r];
        se[r][dd] = (t < 0) ? 0.f : emb[(size_t)t * DIM + dbase + dd];
    }
    __syncthreads();
    float acc[NR];
    #pragma unroll
    for (int r = 0; r < NR; r++) acc[r] = 0.f;
    #pragma unroll 4
    for (int dd = 0; dd < DH; dd++) {
        float w = W1[(size_t)(dbase + dd) * DIM + col];
        #pragma unroll
        for (int r = 0; r < NR; r++) acc[r] += se[r][dd] * w;
    }
    #pragma unroll
    for (int r = 0; r < NR; r++) g_h_part[dc][r][col] = acc[r];
    // fused: zero hist16 for active rows (16384 threads x uint4 = 65536/row)
    int g = (blockIdx.y * gridDim.x + blockIdx.x) * 128 + threadIdx.x;
    uint4 zz = make_uint4(0u, 0u, 0u, 0u);
    for (int r = 0; r < NR; r++) {
        if (g_row_tok[r] >= 0)
            ((uint4*)g_hist16[r])[g] = zz;
    }
}

// combine + tanh: grid 32, block 256
__global__ void k_h_comb() {
    int idx = blockIdx.x * 256 + threadIdx.x;     // 0..8191
    int r = idx >> 10, c = idx & (DIM - 1);
    float v = 0.f;
    #pragma unroll
    for (int dc = 0; dc < NDC_H; dc++) v += g_h_part[dc][r][c];
    g_h[r][c] = tanhf(v);
}

// logits partials: grid (LNBX, NDCL), block 128, float4 columns
__global__ void k_logits_part(const float* __restrict__ Wout) {
    int c  = blockIdx.x * LCOLS_BLK + threadIdx.x * 4;
    int dc = blockIdx.y;
    __shared__ float sh[NR][DL];          // 2 KB
    __shared__ int s_act[NR];
    if (threadIdx.x < NR) s_act[threadIdx.x] = (g_row_tok[threadIdx.x] >= 0);
    for (int i = threadIdx.x; i < NR * DL; i += 128) {
        int r = i >> 6, dd = i & (DL - 1);
        sh[r][dd] = g_h[r][dc * DL + dd];
    }
    __syncthreads();
    if (c >= VOCAB) return;
    float4 acc[NR];
    #pragma unroll
    for (int r = 0; r < NR; r++) acc[r] = make_float4(0.f, 0.f, 0.f, 0.f);
    const float* W = Wout + (size_t)dc * DL * VOCAB + c;
    #pragma unroll 2
    for (int dd = 0; dd < DL; dd++) {
        float4 w = *(const float4*)(W + (size_t)dd * VOCAB);
        #pragma unroll
        for (int r = 0; r < NR; r++) {
            float s = sh[r][dd];
            acc[r].x += s * w.x; acc[r].y += s * w.y;
            acc[r].z += s * w.z; acc[r].w += s * w.w;
        }
    }
    #pragma unroll
    for (int r = 0; r < NR; r++)
        if (s_act[r]) *(float4*)&g_lpart[dc][r][c] = acc[r];
}

// combine + penalty + per-chunk stats + 16-bit histogram: grid NCHUNK, block 256
__global__ void k_comb_stats() {
    int chunk = blockIdx.x;
    int tid = threadIdx.x;
    int c = chunk * 256 + tid;
    __shared__ float sv[256];
    __shared__ int   si[256];
    __shared__ float s_cm;
    __shared__ int   s_ca;
    for (int r = 0; r < NR; r++) {
        if (g_row_tok[r] < 0) continue;
        float v = 0.f;
        #pragma unroll
        for (int dc = 0; dc < NDCL; dc++) v += g_lpart[dc][r][c];
        if (c == EXPAND_ID) v -= 1e9f;
        g_logits[r][c] = v;
        atomicAdd(&g_hist16[r][keyf(v) >> 16], 1u);
        // chunk max + first-index argmax
        sv[tid] = v; si[tid] = c;
        __syncthreads();
        for (int o = 128; o; o >>= 1) {
            if (tid < o) {
                if (sv[tid + o] > sv[tid] ||
                    (sv[tid + o] == sv[tid] && si[tid + o] < si[tid])) {
                    sv[tid] = sv[tid + o]; si[tid] = si[tid + o];
                }
            }
            __syncthreads();
        }
        if (tid == 0) { s_cm = sv[0]; s_ca = si[0]; }
        __syncthreads();
        float cmax = s_cm;
        // chunk z = sum exp(v - cmax)
        sv[tid] = expf(v - cmax);
        __syncthreads();
        for (int o = 128; o; o >>= 1) {
            if (tid < o) sv[tid] += sv[tid + o];
            __syncthreads();
        }
        if (tid == 0) {
            g_cmax[r][chunk]  = cmax;
            g_camax[r][chunk] = s_ca;
            g_cz[r][chunk]    = sv[0];
        }
        __syncthreads();
    }
}

// per-row: reduce chunk stats + histogram scan -> threshold bin: grid NR, block 256
__global__ void k_stats_mid() {
    int r = blockIdx.x;
    if (g_row_tok[r] < 0) return;
    int tid = threadIdx.x;
    __shared__ float sv[256];
    __shared__ int   si[256];
    __shared__ unsigned su[256];
    // global max / first-index argmax over chunks
    float bv = NEGF; int bi = 0x7fffffff;
    if (tid < NCHUNK) { bv = g_cmax[r][tid]; bi = g_camax[r][tid]; }
    sv[tid] = bv; si[tid] = bi;
    __syncthreads();
    for (int o = 128; o; o >>= 1) {
        if (tid < o) {
            if (sv[tid + o] > sv[tid] ||
                (sv[tid + o] == sv[tid] && si[tid + o] < si[tid])) {
                sv[tid] = sv[tid + o]; si[tid] = si[tid + o];
            }
        }
        __syncthreads();
    }
    __shared__ float s_mx; __shared__ int s_am;
    if (tid == 0) { s_mx = sv[0]; s_am = si[0]; }
    __syncthreads();
    float mx = s_mx;
    // Z = sum_c cz[c] * exp(cmax[c] - mx)
    float z = (tid < NCHUNK) ? g_cz[r][tid] * expf(g_cmax[r][tid] - mx) : 0.f;
    sv[tid] = z;
    __syncthreads();
    for (int o = 128; o; o >>= 1) {
        if (tid < o) sv[tid] += sv[tid + o];
        __syncthreads();
    }
    __shared__ float s_Z;
    if (tid == 0) s_Z = sv[0];
    __syncthreads();
    // histogram range sums: thread t owns bins [t*256, t*256+256)
    const uint4* H4 = (const uint4*)&g_hist16[r][tid * 256];
    unsigned local = 0;
    #pragma unroll 8
    for (int i = 0; i < 64; i++) {
        uint4 h = H4[i];
        local += h.x + h.y + h.z + h.w;
    }
    su[tid] = local;
    __syncthreads();
    if (tid == 0) {
        unsigned cum = 0; int t = 255;
        for (; t > 0; t--) {
            if (cum + su[t] >= TOPK) break;
            cum += su[t];
        }
        const unsigned* H = g_hist16[r];
        int T = t * 256;
        for (int b = 255; b >= 0; b--) {
            unsigned cc = H[t * 256 + b];
            if (cum + cc >= TOPK) { T = t * 256 + b; break; }
            cum += cc;
        }
        g_thr[r]    = (unsigned)T;
        g_mx_r[r]   = mx;
        g_Z_r[r]    = s_Z;
        g_amax_r[r] = s_am;
        g_cand_cnt[r] = 0;
    }
}

// gather candidates >= threshold bin: grid (NCHUNK, NR), block 256
__global__ void k_gather() {
    int r = blockIdx.y;
    if (g_row_tok[r] < 0) return;
    int c = blockIdx.x * 256 + threadIdx.x;
    float v = g_logits[r][c];
    if ((keyf(v) >> 16) >= g_thr[r]) {
        int j = atomicAdd(&g_cand_cnt[r], 1);
        if (j < CAND_CAP) g_cand[r][j] = v;
    }
}

// single block, 1024 threads: per-row top-50 sort + conf, then scatter +
// global argmax + reveal + next-step requests
__global__ __launch_bounds__(1024) void k_scatter_select(int step) {
    __shared__ float cand[NR][CAND_CAP];   // 16 KB
    __shared__ float sorted[NR][64];       // 2 KB
    __shared__ float sv[1024];             // 4 KB
    __shared__ int   si[1024];             // 4 KB
    int p = threadIdx.x;
    int r = p >> 7, lane = p & 127;
    int active = (g_row_tok[r] >= 0);
    int n = 0;
    if (active) {
        n = g_cand_cnt[r]; if (n > CAND_CAP) n = CAND_CAP;
        for (int i = lane; i < n; i += 128) cand[r][i] = g_cand[r][i];
    }
    __syncthreads();
    if (active) {
        for (int i = lane; i < n; i += 128) {
            unsigned ki = keyf(cand[r][i]);
            int rank = 0;
            for (int j = 0; j < n; j++) {
                unsigned kj = keyf(cand[r][j]);
                rank += (kj > ki) || (kj == ki && j < i);
            }
            if (rank < 64) sorted[r][rank] = cand[r][i];
        }
    }
    __syncthreads();
    if (active && lane == 0) {
        int m = n; if (m > TOPK) m = TOPK;
        float mx  = g_mx_r[r];
        float run = expf(sorted[r][0] - mx);     // == 1
        float lim = 0.9f * g_Z_r[r];
        for (int j = 1; j < m; j++) {
            if (run > lim) break;                // top-p removal boundary
            run += expf(sorted[r][j] - mx);
        }
        g_row_conf[r] = 1.0f / run;
        g_row_x0[r]   = g_amax_r[r];
    }
    __syncthreads();
    // ---- scatter + argmax + reveal ----
    float myconf;
    if (g_x[p] != MASK_ID) {
        myconf = NEGF; g_conf[p] = NEGF;
    } else {
        myconf = g_conf[p];                       // cached from earlier steps
        int s = p & (SS - 1);
        int t = g_x[(s == 0) ? p : p - 1];
        #pragma unroll
        for (int rr = 0; rr < NR; rr++) {
            if (g_row_tok[rr] == t) {
                myconf = g_row_conf[rr];
                g_conf[p] = myconf;
                g_x0[p]   = g_row_x0[rr];
                g_tok_used[p] = t;
                break;
            }
        }
    }
    sv[p] = myconf; si[p] = p;
    __syncthreads();
    for (int o = 512; o; o >>= 1) {
        if (p < o) {
            if (sv[p + o] > sv[p] ||
                (sv[p + o] == sv[p] && si[p + o] < si[p])) {
                sv[p] = sv[p + o]; si[p] = si[p + o];
            }
        }
        __syncthreads();
    }
    if (p == 0) {
        float c = sv[0]; int idx = si[0];
        g_step_conf[step] = c;
        if (c > 0.f) g_x[idx] = g_x0[idx];        // any-mask guard: conf > 0
    }
    __syncthreads();
    // ---- next-step requests (post-reveal) ----
    if (p < NR) g_row_tok[p] = -1;
    __syncthreads();
    if (g_x[p] != MASK_ID) return;
    int s2 = p & (SS - 1);
    int t2 = g_x[(s2 == 0) ? p : p - 1];
    if (t2 == g_tok_used[p]) return;
    for (int rr = 0; rr < NR; rr++) {
        int old = atomicCAS(&g_row_tok[rr], -1, t2);
        if (old == -1 || old == t2) return;
    }
}

__global__ void k_out(float* __restrict__ out) {
    int i = blockIdx.x * 256 + threadIdx.x;
    if (i < BS) out[i] = (float)g_x[i];
    else if (i < BS + NSTEPS) out[i] = g_step_conf[i - BS];
}

extern "C" void kernel_launch(void* const* d_in, const int* in_sizes, int n_in,
                              void* d_out, int out_size, void* d_ws, size_t ws_size,
                              hipStream_t stream) {
    const int*   x    = (const int*)  d_in[0];
    const float* emb  = (const float*)d_in[1];
    const float* W1   = (const float*)d_in[2];
    const float* Wout = (const float*)d_in[3];

    k_init<<<(BS + 255) / 256, 256, 0, stream>>>(x);
    k_requests<<<1, 1024, 0, stream>>>();
    for (int s = 0; s < NSTEPS; s++) {
        k_h_part<<<dim3(DIM / 128, NDC_H), 128, 0, stream>>>(emb, W1);
        k_h_comb<<<32, 256, 0, stream>>>();
        k_logits_part<<<dim3(LNBX, NDCL), 128, 0, stream>>>(Wout);
        k_comb_stats<<<NCHUNK, 256, 0, stream>>>();
        k_stats_mid<<<NR, 256, 0, stream>>>();
        k_gather<<<dim3(NCHUNK, NR), 256, 0, stream>>>();
        k_scatter_select<<<1, 1024, 0, stream>>>(s);
    }
    k_out<<<(BS + NSTEPS + 255) / 256, 256, 0, stream>>>((float*)d_out);
}

// Round 5
// 335.776 us; speedup vs baseline: 7.0945x; 1.0132x over previous
//
#include <hip/hip_runtime.h>
#include <hip/hip_bf16.h>
#include <math.h>

#define VOCAB 32000
#define DIM 1024
#define BB 2
#define SS 512
#define BS (BB*SS)
#define MASK_ID 31999
#define EXPAND_ID 31998
#define NSTEPS 4
#define TOPK 50
#define NR 8
#define NEGF (-3.4028234663852886e38f)

// h split-K geometry
#define NDC_H 16
#define DH 64
// logits split-K geometry
#define NDCL 16
#define DL 64
#define LCOLS_BLK 512                 // 128 threads * 4 cols
#define LNBX 63                       // ceil(32000/512)
#define NCHUNK 125                    // 32000 / 256
#define CAP 256                       // candidate capacity (LDS)

// -------- persistent device state (re-initialized every kernel_launch) ------
__device__ int      g_x[BS];
__device__ int      g_x0[BS];
__device__ int      g_tok_used[BS];
__device__ float    g_conf[BS];
__device__ int      g_row_tok[NR];     // CAS-compacted: active rows are 0..nact-1
__device__ float    g_row_conf[NR];
__device__ int      g_row_x0[NR];
__device__ float    g_h_part[NDC_H][NR][DIM];
__device__ float    g_lpart[NDCL][NR][VOCAB];
__device__ float    g_logits[NR][VOCAB];
__device__ float    g_step_conf[NSTEPS];
// stats pipeline state
__device__ unsigned g_hist16[NR][65536];
__device__ float    g_cmax[NR][128];
__device__ int      g_camax[NR][128];
__device__ float    g_cz[NR][128];

__device__ inline unsigned keyf(float f) {
    unsigned b = __float_as_uint(f);
    return b ^ ((b & 0x80000000u) ? 0xFFFFFFFFu : 0x80000000u);
}

// 1 block, 1024 threads: init all state + step-0 requests (BS == 1024)
__global__ __launch_bounds__(1024) void k_start(const int* __restrict__ x) {
    int p = threadIdx.x;
    g_x[p] = x[p];
    g_tok_used[p] = -1;
    g_conf[p] = NEGF;
    g_x0[p] = 0;
    if (p < NR) g_row_tok[p] = -1;
    __syncthreads();
    if (g_x[p] != MASK_ID) return;
    int s = p & (SS - 1);
    int t = g_x[(s == 0) ? p : p - 1];
    for (int r = 0; r < NR; r++) {
        int old = atomicCAS(&g_row_tok[r], -1, t);
        if (old == -1 || old == t) return;
    }
}

// h partials + fused histogram zero: grid (DIM/128, NDC_H), block 128
__global__ void k_h_part(const float* __restrict__ emb, const float* __restrict__ W1) {
    int col = blockIdx.x * 128 + threadIdx.x;
    int dc  = blockIdx.y;
    int dbase = dc * DH;
    __shared__ float se[NR][DH];          // 2 KB
    for (int i = threadIdx.x; i < NR * DH; i += 128) {
        int r = i >> 6, dd = i & (DH - 1);
        int t = g_row_tok[r];
        se[r][dd] = (t < 0) ? 0.f : emb[(size_t)t * DIM + dbase + dd];
    }
    __syncthreads();
    float acc[NR];
    #pragma unroll
    for (int r = 0; r < NR; r++) acc[r] = 0.f;
    #pragma unroll 4
    for (int dd = 0; dd < DH; dd++) {
        float w = W1[(size_t)(dbase + dd) * DIM + col];
        #pragma unroll
        for (int r = 0; r < NR; r++) acc[r] += se[r][dd] * w;
    }
    #pragma unroll
    for (int r = 0; r < NR; r++) g_h_part[dc][r][col] = acc[r];
    // fused: zero hist16 for active rows (16384 threads x uint4 = 65536/row)
    int g = (blockIdx.y * gridDim.x + blockIdx.x) * 128 + threadIdx.x;
    uint4 zz = make_uint4(0u, 0u, 0u, 0u);
    for (int r = 0; r < NR; r++) {
        if (g_row_tok[r] >= 0)
            ((uint4*)g_hist16[r])[g] = zz;
    }
}

// row-count-specialized accumulate + store (compile-time reg indices only)
template<int NA>
__device__ __forceinline__ void accum_rows(const float* __restrict__ W,
                                           const float (*sh)[DL],
                                           float* __restrict__ lp_base, int c) {
    float4 acc[NA];
    #pragma unroll
    for (int r = 0; r < NA; r++) acc[r] = make_float4(0.f, 0.f, 0.f, 0.f);
    #pragma unroll 4
    for (int dd = 0; dd < DL; dd++) {
        float4 w = *(const float4*)(W + (size_t)dd * VOCAB);
        #pragma unroll
        for (int r = 0; r < NA; r++) {
            float s = sh[r][dd];
            acc[r].x += s * w.x; acc[r].y += s * w.y;
            acc[r].z += s * w.z; acc[r].w += s * w.w;
        }
    }
    #pragma unroll
    for (int r = 0; r < NA; r++)
        *(float4*)(lp_base + (size_t)r * VOCAB + c) = acc[r];
}

// logits partials with fused h-combine+tanh: grid (LNBX, NDCL), block 128
__global__ void k_logits_fused(const float* __restrict__ Wout) {
    int c  = blockIdx.x * LCOLS_BLK + threadIdx.x * 4;
    int dc = blockIdx.y;
    __shared__ float sh[NR][DL];          // 2 KB
    __shared__ int s_nact;
    if (threadIdx.x == 0) {
        int n = 0;
        while (n < NR && g_row_tok[n] >= 0) n++;
        s_nact = n;
    }
    __syncthreads();
    int nact = s_nact;
    // fused h-combine: sh[r][dd] = tanh(sum_hc h_part[hc][r][dc*DL+dd])
    for (int i = threadIdx.x; i < NR * DL; i += 128) {
        int r = i >> 6, dd = i & (DL - 1);
        float s = 0.f;
        if (r < nact) {
            int dcol = dc * DL + dd;
            #pragma unroll
            for (int hc = 0; hc < NDC_H; hc++) s += g_h_part[hc][r][dcol];
            s = tanhf(s);
        }
        sh[r][dd] = s;
    }
    __syncthreads();
    if (c >= VOCAB) return;
    const float* W = Wout + (size_t)dc * DL * VOCAB + c;
    float* lp = &g_lpart[dc][0][0];
    if      (nact == 1) accum_rows<1>(W, sh, lp, c);
    else if (nact == 2) accum_rows<2>(W, sh, lp, c);
    else if (nact == 3) accum_rows<3>(W, sh, lp, c);
    else if (nact == 4) accum_rows<4>(W, sh, lp, c);
    else                accum_rows<NR>(W, sh, lp, c);
}

// combine + penalty + chunk stats + 16-bit hist: grid (NCHUNK, NR), block 256
__global__ void k_comb_stats() {
    int r = blockIdx.y;
    if (g_row_tok[r] < 0) return;
    int chunk = blockIdx.x;
    int tid = threadIdx.x;
    int c = chunk * 256 + tid;
    __shared__ float sv[256];
    __shared__ int   si[256];
    __shared__ float s_cm;
    __shared__ int   s_ca;
    float v = 0.f;
    #pragma unroll
    for (int dc = 0; dc < NDCL; dc++) v += g_lpart[dc][r][c];
    if (c == EXPAND_ID) v -= 1e9f;
    g_logits[r][c] = v;
    atomicAdd(&g_hist16[r][keyf(v) >> 16], 1u);
    // chunk max + first-index argmax
    sv[tid] = v; si[tid] = c;
    __syncthreads();
    for (int o = 128; o; o >>= 1) {
        if (tid < o) {
            if (sv[tid + o] > sv[tid] ||
                (sv[tid + o] == sv[tid] && si[tid + o] < si[tid])) {
                sv[tid] = sv[tid + o]; si[tid] = si[tid + o];
            }
        }
        __syncthreads();
    }
    if (tid == 0) { s_cm = sv[0]; s_ca = si[0]; }
    __syncthreads();
    float cmax = s_cm;
    sv[tid] = expf(v - cmax);
    __syncthreads();
    for (int o = 128; o; o >>= 1) {
        if (tid < o) sv[tid] += sv[tid + o];
        __syncthreads();
    }
    if (tid == 0) {
        g_cmax[r][chunk]  = cmax;
        g_camax[r][chunk] = s_ca;
        g_cz[r][chunk]    = sv[0];
    }
}

// 1 block, 1024 threads: chunk-reduce, hist scan, gather, sort+conf,
// scatter, global argmax, reveal, next-step requests.
__global__ __launch_bounds__(1024) void k_finish(int step) {
    __shared__ float    red_f[1024];
    __shared__ int      red_i[1024];
    __shared__ unsigned su_[1024];
    __shared__ unsigned sup[32];
    __shared__ float    cand[NR][CAP];     // 8 KB
    __shared__ int      cand_n[NR];
    __shared__ float    sorted[NR][TOPK];
    __shared__ float    s_mx[NR];
    __shared__ int      s_am[NR];
    __shared__ float    s_Zr[NR];
    __shared__ unsigned s_thr[NR];
    __shared__ int      s_nact;

    int tid = threadIdx.x;
    if (tid == 0) {
        int n = 0;
        while (n < NR && g_row_tok[n] >= 0) n++;
        s_nact = n;
    }
    if (tid < NR) cand_n[tid] = 0;
    __syncthreads();
    int nact = s_nact;
    int r = tid >> 7, lane = tid & 127;
    bool act = (r < nact);

    // --- Phase A: per-row chunk reduce (128-lane group per row) ---
    float bv = NEGF; int bi = 0x7fffffff;
    if (act && lane < NCHUNK) { bv = g_cmax[r][lane]; bi = g_camax[r][lane]; }
    red_f[tid] = bv; red_i[tid] = bi;
    __syncthreads();
    for (int o = 64; o; o >>= 1) {
        if (lane < o) {
            if (red_f[tid + o] > red_f[tid] ||
                (red_f[tid + o] == red_f[tid] && red_i[tid + o] < red_i[tid])) {
                red_f[tid] = red_f[tid + o]; red_i[tid] = red_i[tid + o];
            }
        }
        __syncthreads();
    }
    if (act && lane == 0) { s_mx[r] = red_f[tid]; s_am[r] = red_i[tid]; }
    __syncthreads();
    float z = 0.f;
    if (act && lane < NCHUNK) z = g_cz[r][lane] * expf(g_cmax[r][lane] - s_mx[r]);
    red_f[tid] = z;
    __syncthreads();
    for (int o = 64; o; o >>= 1) {
        if (lane < o) red_f[tid] += red_f[tid + o];
        __syncthreads();
    }
    if (act && lane == 0) s_Zr[r] = red_f[tid];
    __syncthreads();

    // --- Phase B: hist threshold-bin scan (rows serial, all threads) ---
    for (int rr = 0; rr < nact; rr++) {
        const uint4* H4 = (const uint4*)&g_hist16[rr][tid * 64];
        unsigned loc = 0;
        #pragma unroll
        for (int i = 0; i < 16; i++) {
            uint4 h = H4[i];
            loc += h.x + h.y + h.z + h.w;
        }
        su_[tid] = loc;
        __syncthreads();
        if (tid < 32) {
            unsigned s2 = 0;
            for (int j = 0; j < 32; j++) s2 += su_[tid * 32 + j];
            sup[tid] = s2;
        }
        __syncthreads();
        if (tid == 0) {
            unsigned cum = 0; int w = 31;
            for (; w > 0; w--) { if (cum + sup[w] >= TOPK) break; cum += sup[w]; }
            int j = w * 32 + 31;
            for (; j > w * 32; j--) { if (cum + su_[j] >= TOPK) break; cum += su_[j]; }
            const unsigned* H = g_hist16[rr];
            int T = j * 64;
            for (int b = j * 64 + 63; b >= j * 64; b--) {
                unsigned cc = H[b];
                if (cum + cc >= TOPK) { T = b; break; }
                cum += cc;
            }
            s_thr[rr] = (unsigned)T;
        }
        __syncthreads();
    }

    // --- Phase C: gather candidates >= threshold bin (rows serial) ---
    for (int rr = 0; rr < nact; rr++) {
        unsigned T = s_thr[rr];
        const float4* L4 = (const float4*)g_logits[rr];
        #pragma unroll
        for (int i = 0; i < 8; i++) {
            int idx = i * 1024 + tid;
            if (idx < VOCAB / 4) {
                float4 v4 = L4[idx];
                float vv[4] = {v4.x, v4.y, v4.z, v4.w};
                #pragma unroll
                for (int q = 0; q < 4; q++) {
                    if ((keyf(vv[q]) >> 16) >= T) {
                        int j = atomicAdd(&cand_n[rr], 1);
                        if (j < CAP) cand[rr][j] = vv[q];
                    }
                }
            }
        }
    }
    __syncthreads();

    // --- Phase D: rank-sort top-50 + conf (128-lane group per row) ---
    if (act) {
        int n = cand_n[r]; if (n > CAP) n = CAP;
        for (int i = lane; i < n; i += 128) {
            unsigned ki = keyf(cand[r][i]);
            int rank = 0;
            for (int j = 0; j < n; j++) {
                unsigned kj = keyf(cand[r][j]);
                rank += (kj > ki) || (kj == ki && j < i);
            }
            if (rank < TOPK) sorted[r][rank] = cand[r][i];
        }
    }
    __syncthreads();
    if (act && lane == 0) {
        int n = cand_n[r]; if (n > CAP) n = CAP;
        int m = n; if (m > TOPK) m = TOPK;
        float mx  = s_mx[r];
        float run = expf(sorted[r][0] - mx);     // == 1
        float lim = 0.9f * s_Zr[r];
        for (int j = 1; j < m; j++) {
            if (run > lim) break;                // top-p removal boundary
            run += expf(sorted[r][j] - mx);
        }
        g_row_conf[r] = 1.0f / run;
        g_row_x0[r]   = s_am[r];
    }
    __syncthreads();

    // --- Phase E: scatter + global argmax + reveal + next requests ---
    int p = tid;
    float myconf;
    if (g_x[p] != MASK_ID) {
        myconf = NEGF; g_conf[p] = NEGF;
    } else {
        myconf = g_conf[p];                       // cached from earlier steps
        int s = p & (SS - 1);
        int t = g_x[(s == 0) ? p : p - 1];
        #pragma unroll
        for (int rr = 0; rr < NR; rr++) {
            if (g_row_tok[rr] == t) {
                myconf = g_row_conf[rr];
                g_conf[p] = myconf;
                g_x0[p]   = g_row_x0[rr];
                g_tok_used[p] = t;
                break;
            }
        }
    }
    red_f[p] = myconf; red_i[p] = p;
    __syncthreads();
    for (int o = 512; o; o >>= 1) {
        if (p < o) {
            if (red_f[p + o] > red_f[p] ||
                (red_f[p + o] == red_f[p] && red_i[p + o] < red_i[p])) {
                red_f[p] = red_f[p + o]; red_i[p] = red_i[p + o];
            }
        }
        __syncthreads();
    }
    if (p == 0) {
        float c = red_f[0]; int idx = red_i[0];
        g_step_conf[step] = c;
        if (c > 0.f) g_x[idx] = g_x0[idx];        // any-mask guard: conf > 0
    }
    __syncthreads();
    // next-step requests (post-reveal)
    if (p < NR) g_row_tok[p] = -1;
    __syncthreads();
    if (g_x[p] != MASK_ID) return;
    int s2 = p & (SS - 1);
    int t2 = g_x[(s2 == 0) ? p : p - 1];
    if (t2 == g_tok_used[p]) return;
    for (int rr = 0; rr < NR; rr++) {
        int old = atomicCAS(&g_row_tok[rr], -1, t2);
        if (old == -1 || old == t2) return;
    }
}

__global__ void k_out(float* __restrict__ out) {
    int i = blockIdx.x * 256 + threadIdx.x;
    if (i < BS) out[i] = (float)g_x[i];
    else if (i < BS + NSTEPS) out[i] = g_step_conf[i - BS];
}

extern "C" void kernel_launch(void* const* d_in, const int* in_sizes, int n_in,
                              void* d_out, int out_size, void* d_ws, size_t ws_size,
                              hipStream_t stream) {
    const int*   x    = (const int*)  d_in[0];
    const float* emb  = (const float*)d_in[1];
    const float* W1   = (const float*)d_in[2];
    const float* Wout = (const float*)d_in[3];

    k_start<<<1, 1024, 0, stream>>>(x);
    for (int s = 0; s < NSTEPS; s++) {
        k_h_part<<<dim3(DIM / 128, NDC_H), 128, 0, stream>>>(emb, W1);
        k_logits_fused<<<dim3(LNBX, NDCL), 128, 0, stream>>>(Wout);
        k_comb_stats<<<dim3(NCHUNK, NR), 256, 0, stream>>>();
        k_finish<<<1, 1024, 0, stream>>>(s);
    }
    k_out<<<(BS + NSTEPS + 255) / 256, 256, 0, stream>>>((float*)d_out);
}